// Round 8
// baseline (551.797 us; speedup 1.0000x reference)
//
#include <hip/hip_runtime.h>
#include <hip/hip_bf16.h>
#include <cstddef>

#define GN 50000
#define GE 800000
#define GH 4
#define GD 32
#define SLOPE 0.2f

typedef unsigned short ushort_t;
typedef unsigned int uint_t;
using short8 = __attribute__((ext_vector_type(8))) short;
using float4v = __attribute__((ext_vector_type(4))) float;

__device__ __forceinline__ ushort_t f2bf(float f) {
    union { float f; uint_t u; } v; v.f = f;
    uint_t r = v.u + 0x7fff + ((v.u >> 16) & 1);   // RNE
    return (ushort_t)(r >> 16);
}
__device__ __forceinline__ float bflo(uint_t u) { return __uint_as_float(u << 16); }
__device__ __forceinline__ float bfhi(uint_t u) { return __uint_as_float(u & 0xffff0000u); }
__device__ __forceinline__ float bfu(ushort_t u) { return __uint_as_float((uint_t)u << 16); }

// ---------------- CSR build ----------------
__global__ void k_hist(const int* __restrict__ dst, int* __restrict__ deg, int E) {
    int i = blockIdx.x * 256 + threadIdx.x;
    if (i < E) atomicAdd(&deg[dst[i]], 1);
}

__global__ void k_scan1(const int* __restrict__ deg, int* __restrict__ row_ptr,
                        int* __restrict__ partials, int n) {
    __shared__ int s[256];
    int t = threadIdx.x;
    int i = blockIdx.x * 256 + t;
    int v = (i < n) ? deg[i] : 0;
    s[t] = v;
    __syncthreads();
    for (int off = 1; off < 256; off <<= 1) {
        int add = (t >= off) ? s[t - off] : 0;
        __syncthreads();
        s[t] += add;
        __syncthreads();
    }
    if (i < n) row_ptr[i] = s[t] - v;
    if (t == 255) partials[blockIdx.x] = s[255];
}

__global__ void k_scan2(int* __restrict__ partials, int nb) {
    __shared__ int s[256];
    int t = threadIdx.x;
    int v = (t < nb) ? partials[t] : 0;
    s[t] = v;
    __syncthreads();
    for (int off = 1; off < 256; off <<= 1) {
        int add = (t >= off) ? s[t - off] : 0;
        __syncthreads();
        s[t] += add;
        __syncthreads();
    }
    if (t < nb) partials[t] = s[t] - v;
}

__global__ void k_scan3(int* __restrict__ row_ptr, int* __restrict__ wpos,
                        const int* __restrict__ partials, int n, int E) {
    int i = blockIdx.x * 256 + threadIdx.x;
    if (i < n) {
        int rp = row_ptr[i] + partials[i >> 8];
        row_ptr[i] = rp;
        wpos[i] = rp;
        if (i == 0) row_ptr[n] = E;
    }
}

__global__ void k_fill(const int* __restrict__ src, const int* __restrict__ dst,
                       int* __restrict__ wpos, int* __restrict__ csr_src, int E) {
    int i = blockIdx.x * 256 + threadIdx.x;
    if (i < E) {
        int p = atomicAdd(&wpos[dst[i]], 1);
        csr_src[p] = src[i];
    }
}

// ---------------- weight transpose+convert ----------------
__global__ void k_cvt_w(const float* __restrict__ W0, const float* __restrict__ W1,
                        ushort_t* __restrict__ wbt) {
    int t = blockIdx.x * 256 + threadIdx.x;   // 0..32767
    int m = t >> 14;
    int o = t & 16383;
    int n = o >> 7, k = o & 127;
    const float* W = m ? W1 : W0;
    wbt[t] = f2bf(W[k * 128 + n]);
}

// ---- fused el/er epilogue over MFMA accumulator ----
__device__ __forceinline__ void lr_epilogue(const float4v acc[2][8],
                                            const float* __restrict__ al,
                                            const float* __restrict__ ar,
                                            float* __restrict__ el,
                                            float* __restrict__ er,
                                            int r0, int quad, int col, int M) {
#pragma unroll
    for (int rt = 0; rt < 2; rt++) {
#pragma unroll
        for (int h = 0; h < 4; h++) {
            float alv0 = al[h * 32 + col], alv1 = al[h * 32 + 16 + col];
            float arv0 = ar[h * 32 + col], arv1 = ar[h * 32 + 16 + col];
            float pl[4], pr[4];
#pragma unroll
            for (int r = 0; r < 4; r++) {
                pl[r] = acc[rt][2 * h][r] * alv0 + acc[rt][2 * h + 1][r] * alv1;
                pr[r] = acc[rt][2 * h][r] * arv0 + acc[rt][2 * h + 1][r] * arv1;
            }
#pragma unroll
            for (int m = 1; m < 16; m <<= 1) {
#pragma unroll
                for (int r = 0; r < 4; r++) {
                    pl[r] += __shfl_xor(pl[r], m, 64);
                    pr[r] += __shfl_xor(pr[r], m, 64);
                }
            }
            if (col == h) {
#pragma unroll
                for (int r = 0; r < 4; r++) {
                    int row = r0 + rt * 16 + quad * 4 + r;
                    if (row < M) el[row * 4 + h] = pl[r];
                }
            }
            if (col == 8 + h) {
#pragma unroll
                for (int r = 0; r < 4; r++) {
                    int row = r0 + rt * 16 + quad * 4 + r;
                    if (row < M) er[row * 4 + h] = pr[r];
                }
            }
        }
    }
}

// ---------------- MFMA GEMM (fp32 A, layer 1) + fused el/er ----------------
__global__ __launch_bounds__(256) void gemm_mfma32(const float* __restrict__ A0,
                                                   const float* __restrict__ A1,
                                                   const ushort_t* __restrict__ WbT,
                                                   const float* __restrict__ al,
                                                   const float* __restrict__ ar,
                                                   ushort_t* __restrict__ Cb,
                                                   float* __restrict__ el,
                                                   float* __restrict__ er, int M) {
    __shared__ ushort_t Bs[128][136];
    int tid = threadIdx.x;
    for (int i = tid; i < 128 * 16; i += 256) {
        int n = i >> 4;
        int kc = (i & 15) << 3;
        *(short8*)&Bs[n][kc] = *(const short8*)&WbT[n * 128 + kc];
    }
    __syncthreads();
    int wid = tid >> 6, lane = tid & 63;
    int r0 = blockIdx.x * 128 + wid * 32;
    int col = lane & 15, quad = lane >> 4;
    float4v acc[2][8];
#pragma unroll
    for (int rt = 0; rt < 2; rt++)
#pragma unroll
        for (int t = 0; t < 8; t++) acc[rt][t] = (float4v){0.f, 0.f, 0.f, 0.f};
    int ar_[2] = {r0 + col, r0 + 16 + col};
    const float* Ap[2];
#pragma unroll
    for (int rt = 0; rt < 2; rt++) {
        int a = ar_[rt];
        Ap[rt] = (a < M) ? ((a < GN) ? (A0 + (size_t)a * 128)
                                     : (A1 + (size_t)(a - GN) * 128)) : nullptr;
    }
#pragma unroll
    for (int ks = 0; ks < 4; ks++) {
        short8 af[2];
#pragma unroll
        for (int rt = 0; rt < 2; rt++) {
            af[rt] = (short8){};
            if (Ap[rt]) {
                float4 v0 = *(const float4*)&Ap[rt][ks * 32 + quad * 8];
                float4 v1 = *(const float4*)&Ap[rt][ks * 32 + quad * 8 + 4];
                af[rt][0] = (short)f2bf(v0.x); af[rt][1] = (short)f2bf(v0.y);
                af[rt][2] = (short)f2bf(v0.z); af[rt][3] = (short)f2bf(v0.w);
                af[rt][4] = (short)f2bf(v1.x); af[rt][5] = (short)f2bf(v1.y);
                af[rt][6] = (short)f2bf(v1.z); af[rt][7] = (short)f2bf(v1.w);
            }
        }
#pragma unroll
        for (int nt = 0; nt < 8; nt++) {
            short8 bf = *(const short8*)&Bs[nt * 16 + col][ks * 32 + quad * 8];
            acc[0][nt] = __builtin_amdgcn_mfma_f32_16x16x32_bf16(af[0], bf, acc[0][nt], 0, 0, 0);
            acc[1][nt] = __builtin_amdgcn_mfma_f32_16x16x32_bf16(af[1], bf, acc[1][nt], 0, 0, 0);
        }
    }
#pragma unroll
    for (int rt = 0; rt < 2; rt++)
#pragma unroll
        for (int nt = 0; nt < 8; nt++)
#pragma unroll
            for (int r = 0; r < 4; r++) {
                int row = r0 + rt * 16 + quad * 4 + r;
                if (row < M) Cb[(size_t)row * 128 + nt * 16 + col] = f2bf(acc[rt][nt][r]);
            }
    lr_epilogue(acc, al, ar, el, er, r0, quad, col, M);
}

// ---------------- MFMA GEMM (bf16 A, layer 2) + fused el/er ----------------
__global__ __launch_bounds__(256) void gemm_mfma(const ushort_t* __restrict__ A,
                                                 const ushort_t* __restrict__ WbT,
                                                 const float* __restrict__ al,
                                                 const float* __restrict__ ar,
                                                 ushort_t* __restrict__ Cb,
                                                 float* __restrict__ el,
                                                 float* __restrict__ er, int M) {
    __shared__ ushort_t Bs[128][136];
    int tid = threadIdx.x;
    for (int i = tid; i < 128 * 16; i += 256) {
        int n = i >> 4;
        int kc = (i & 15) << 3;
        *(short8*)&Bs[n][kc] = *(const short8*)&WbT[n * 128 + kc];
    }
    __syncthreads();
    int wid = tid >> 6, lane = tid & 63;
    int r0 = blockIdx.x * 128 + wid * 32;
    int col = lane & 15, quad = lane >> 4;
    float4v acc[2][8];
#pragma unroll
    for (int rt = 0; rt < 2; rt++)
#pragma unroll
        for (int t = 0; t < 8; t++) acc[rt][t] = (float4v){0.f, 0.f, 0.f, 0.f};
    int ar_[2] = {r0 + col, r0 + 16 + col};
#pragma unroll
    for (int ks = 0; ks < 4; ks++) {
        short8 af[2];
#pragma unroll
        for (int rt = 0; rt < 2; rt++) {
            af[rt] = (short8){};
            if (ar_[rt] < M) af[rt] = *(const short8*)&A[(size_t)ar_[rt] * 128 + ks * 32 + quad * 8];
        }
#pragma unroll
        for (int nt = 0; nt < 8; nt++) {
            short8 bf = *(const short8*)&Bs[nt * 16 + col][ks * 32 + quad * 8];
            acc[0][nt] = __builtin_amdgcn_mfma_f32_16x16x32_bf16(af[0], bf, acc[0][nt], 0, 0, 0);
            acc[1][nt] = __builtin_amdgcn_mfma_f32_16x16x32_bf16(af[1], bf, acc[1][nt], 0, 0, 0);
        }
    }
#pragma unroll
    for (int rt = 0; rt < 2; rt++)
#pragma unroll
        for (int nt = 0; nt < 8; nt++)
#pragma unroll
            for (int r = 0; r < 4; r++) {
                int row = r0 + rt * 16 + quad * 4 + r;
                if (row < M) Cb[(size_t)row * 128 + nt * 16 + col] = f2bf(acc[rt][nt][r]);
            }
    lr_epilogue(acc, al, ar, el, er, r0, quad, col, M);
}

// ---- shared agg gather core: one wave per node, lanes 0-31 path0, 32-63 path1.
// lane q owns dims 4q..4q+3; head=q>>3. Softmax weight computed in-place
// (exp(leaky(el+er)), no max-sub: |e| small). Returns post-softmax v0..v3.
__device__ __forceinline__ void agg_core(
    const ushort_t* __restrict__ featb, const float* __restrict__ el, float ern,
    const int* __restrict__ csr_src, int base, int deg, int head, int q4,
    float& v0, float& v1, float& v2, float& v3) {
    float a0 = 0.f, a1 = 0.f, a2 = 0.f, a3 = 0.f, ss = 0.f;
    int i = 0;
    for (; i + 8 <= deg; i += 8) {
        int j = base + i;
        int s0 = csr_src[j + 0], s1 = csr_src[j + 1], s2 = csr_src[j + 2], s3 = csr_src[j + 3];
        int s4 = csr_src[j + 4], s5 = csr_src[j + 5], s6 = csr_src[j + 6], s7 = csr_src[j + 7];
        float e0 = el[s0 * 4 + head] + ern;
        float e1 = el[s1 * 4 + head] + ern;
        float e2 = el[s2 * 4 + head] + ern;
        float e3 = el[s3 * 4 + head] + ern;
        float e4 = el[s4 * 4 + head] + ern;
        float e5 = el[s5 * 4 + head] + ern;
        float e6 = el[s6 * 4 + head] + ern;
        float e7 = el[s7 * 4 + head] + ern;
        uint2 f0 = *(const uint2*)&featb[s0 * 128 + q4];
        uint2 f1 = *(const uint2*)&featb[s1 * 128 + q4];
        uint2 f2 = *(const uint2*)&featb[s2 * 128 + q4];
        uint2 f3 = *(const uint2*)&featb[s3 * 128 + q4];
        uint2 f4 = *(const uint2*)&featb[s4 * 128 + q4];
        uint2 f5 = *(const uint2*)&featb[s5 * 128 + q4];
        uint2 f6 = *(const uint2*)&featb[s6 * 128 + q4];
        uint2 f7 = *(const uint2*)&featb[s7 * 128 + q4];
        e0 = e0 > 0.f ? e0 : SLOPE * e0;
        e1 = e1 > 0.f ? e1 : SLOPE * e1;
        e2 = e2 > 0.f ? e2 : SLOPE * e2;
        e3 = e3 > 0.f ? e3 : SLOPE * e3;
        e4 = e4 > 0.f ? e4 : SLOPE * e4;
        e5 = e5 > 0.f ? e5 : SLOPE * e5;
        e6 = e6 > 0.f ? e6 : SLOPE * e6;
        e7 = e7 > 0.f ? e7 : SLOPE * e7;
        float w0 = __expf(e0), w1 = __expf(e1), w2 = __expf(e2), w3 = __expf(e3);
        float w4 = __expf(e4), w5 = __expf(e5), w6 = __expf(e6), w7 = __expf(e7);
        ss += ((w0 + w1) + (w2 + w3)) + ((w4 + w5) + (w6 + w7));
        a0 += w0 * bflo(f0.x) + w1 * bflo(f1.x) + w2 * bflo(f2.x) + w3 * bflo(f3.x) +
              w4 * bflo(f4.x) + w5 * bflo(f5.x) + w6 * bflo(f6.x) + w7 * bflo(f7.x);
        a1 += w0 * bfhi(f0.x) + w1 * bfhi(f1.x) + w2 * bfhi(f2.x) + w3 * bfhi(f3.x) +
              w4 * bfhi(f4.x) + w5 * bfhi(f5.x) + w6 * bfhi(f6.x) + w7 * bfhi(f7.x);
        a2 += w0 * bflo(f0.y) + w1 * bflo(f1.y) + w2 * bflo(f2.y) + w3 * bflo(f3.y) +
              w4 * bflo(f4.y) + w5 * bflo(f5.y) + w6 * bflo(f6.y) + w7 * bflo(f7.y);
        a3 += w0 * bfhi(f0.y) + w1 * bfhi(f1.y) + w2 * bfhi(f2.y) + w3 * bfhi(f3.y) +
              w4 * bfhi(f4.y) + w5 * bfhi(f5.y) + w6 * bfhi(f6.y) + w7 * bfhi(f7.y);
    }
    for (; i < deg; i++) {
        int j = base + i;
        int s = csr_src[j];
        float e = el[s * 4 + head] + ern;
        uint2 f = *(const uint2*)&featb[s * 128 + q4];
        e = e > 0.f ? e : SLOPE * e;
        float w = __expf(e);
        ss += w;
        a0 += w * bflo(f.x);
        a1 += w * bfhi(f.x);
        a2 += w * bflo(f.y);
        a3 += w * bfhi(f.y);
    }
    float inv = (deg > 0) ? 1.f / ss : 0.f;
    v0 = a0 * inv; v1 = a1 * inv; v2 = a2 * inv; v3 = a3 * inv;
}

// ---------------- layer-1 aggregate: -> abuf (bf16) ----------------
__global__ __launch_bounds__(256) void gat_agg_l1(
    const ushort_t* __restrict__ featb, const float* __restrict__ el,
    const float* __restrict__ er, const int* __restrict__ row_ptr,
    const int* __restrict__ csr_src, ushort_t* __restrict__ abuf) {
    int n = blockIdx.x * 4 + (threadIdx.x >> 6);
    if (n >= GN) return;
    int lane = threadIdx.x & 63;
    int half = lane >> 5;
    int q = lane & 31;
    int head = q >> 3, q4 = q << 2;
    const ushort_t* fb = featb + (size_t)half * (GN * 128);
    const float* elp = el + (size_t)half * (GN * 4);
    float ern = er[((size_t)n + (size_t)half * GN) * 4 + head];
    int base = row_ptr[n];
    int deg = row_ptr[n + 1] - base;
    float v0, v1, v2, v3;
    agg_core(fb, elp, ern, csr_src, base, deg, head, q4, v0, v1, v2, v3);
    v0 = v0 > 0.f ? v0 : __expf(v0) - 1.f;
    v1 = v1 > 0.f ? v1 : __expf(v1) - 1.f;
    v2 = v2 > 0.f ? v2 : __expf(v2) - 1.f;
    v3 = v3 > 0.f ? v3 : __expf(v3) - 1.f;
    size_t idx = ((size_t)n + (size_t)half * GN) * 128 + q4;
    ushort4 o;
    o.x = f2bf(v0); o.y = f2bf(v1); o.z = f2bf(v2); o.w = f2bf(v3);
    *(ushort4*)&abuf[idx] = o;
}

// ---------------- layer-2 aggregate + residual + ELU + mixup + h + logits ----------------
__global__ __launch_bounds__(256) void gat_agg_l2(
    const ushort_t* __restrict__ featb, const float* __restrict__ el,
    const float* __restrict__ er, const int* __restrict__ row_ptr,
    const int* __restrict__ csr_src, const ushort_t* __restrict__ resid,
    const float* __restrict__ Wout, const float* __restrict__ bout,
    const float* __restrict__ lamb, float* __restrict__ outh,
    float* __restrict__ outlog) {
    __shared__ float WsT[40 * 128];   // WsT[c][k] = Wout[k*40+c]
    __shared__ float bs[40];
    __shared__ float hs[4][128];
    int tid = threadIdx.x;
    for (int i = tid; i < 40 * 128; i += 256) {
        int c = i >> 7, k = i & 127;
        WsT[i] = Wout[k * 40 + c];
    }
    if (tid < 40) bs[tid] = bout[tid];
    __syncthreads();
    int n = blockIdx.x * 4 + (tid >> 6);
    if (n >= GN) return;
    int w = tid >> 6;
    int lane = tid & 63;
    int half = lane >> 5;
    int q = lane & 31;
    int head = q >> 3, q4 = q << 2;
    const ushort_t* fb = featb + (size_t)half * (GN * 128);
    const float* elp = el + (size_t)half * (GN * 4);
    float ern = er[((size_t)n + (size_t)half * GN) * 4 + head];
    int base = row_ptr[n];
    int deg = row_ptr[n + 1] - base;
    float v0, v1, v2, v3;
    agg_core(fb, elp, ern, csr_src, base, deg, head, q4, v0, v1, v2, v3);
    // residual (bf16) + ELU
    size_t idx = ((size_t)n + (size_t)half * GN) * 128 + q4;
    ushort4 r = *(const ushort4*)&resid[idx];
    v0 += bfu(r.x); v1 += bfu(r.y); v2 += bfu(r.z); v3 += bfu(r.w);
    v0 = v0 > 0.f ? v0 : __expf(v0) - 1.f;
    v1 = v1 > 0.f ? v1 : __expf(v1) - 1.f;
    v2 = v2 > 0.f ? v2 : __expf(v2) - 1.f;
    v3 = v3 > 0.f ? v3 : __expf(v3) - 1.f;
    // mixup across halves (partner lane = lane ^ 32)
    float p0 = __shfl_xor(v0, 32, 64);
    float p1 = __shfl_xor(v1, 32, 64);
    float p2 = __shfl_xor(v2, 32, 64);
    float p3 = __shfl_xor(v3, 32, 64);
    float lam = lamb[0];
    if (half == 0) {
        float m0 = lam * v0 + (1.f - lam) * p0;
        float m1 = lam * v1 + (1.f - lam) * p1;
        float m2 = lam * v2 + (1.f - lam) * p2;
        float m3 = lam * v3 + (1.f - lam) * p3;
        *(float4*)&outh[(size_t)n * 128 + q4] = make_float4(m0, m1, m2, m3);
        *(float4*)&hs[w][q4] = make_float4(m0, m1, m2, m3);
    }
    // logits: lanes 0..39 each compute one class (same-wave LDS, no barrier)
    if (lane < 40) {
        float acc = bs[lane];
        const float* wr = &WsT[lane * 128];
#pragma unroll
        for (int k = 0; k < 128; k += 4) {
            float4 hv = *(const float4*)&hs[w][k];
            float4 wv = *(const float4*)&wr[k];
            acc += hv.x * wv.x + hv.y * wv.y + hv.z * wv.z + hv.w * wv.w;
        }
        outlog[(size_t)n * 40 + lane] = acc;
    }
}

extern "C" void kernel_launch(void* const* d_in, const int* in_sizes, int n_in,
                              void* d_out, int out_size, void* d_ws, size_t ws_size,
                              hipStream_t stream) {
    const float* inputs = (const float*)d_in[0];
    const float* target = (const float*)d_in[1];
    const float* lamb   = (const float*)d_in[2];
    const float* W0     = (const float*)d_in[3];
    const float* al0    = (const float*)d_in[4];
    const float* ar0    = (const float*)d_in[5];
    const float* W1     = (const float*)d_in[6];
    const float* al1    = (const float*)d_in[7];
    const float* ar1    = (const float*)d_in[8];
    const float* Wout   = (const float*)d_in[9];
    const float* bout   = (const float*)d_in[10];
    const int*   src    = (const int*)d_in[11];
    const int*   dst    = (const int*)d_in[12];

    float* out = (float*)d_out;
    float* outh = out;                          // [N,128]
    float* outlog = out + (size_t)GN * 128;     // [N,40]

    const int NP = 2 * GN;
    // workspace layout
    ushort_t* featb = (ushort_t*)d_ws;                    // [2N,128] bf16
    ushort_t* abuf  = featb + (size_t)NP * 128;           // [2N,128] bf16 (layer1 out / resid)
    float* el = (float*)(abuf + (size_t)NP * 128);        // [2N,4]
    float* er = el + (size_t)NP * GH;                     // [2N,4]
    ushort_t* wbt = (ushort_t*)(er + (size_t)NP * GH);    // [2][128][128] bf16
    int* row_ptr  = (int*)(wbt + 2 * 128 * 128);          // N+1
    int* wpos     = row_ptr + (GN + 1);                   // N
    int* csr_src  = wpos + GN;                            // E (+pad)
    int* partials = csr_src + GE + 16;                    // 256

    const int nb = (GN + 255) / 256;
    const int eb = (GE + 255) / 256;
    const int gblocks = (NP + 127) / 128;
    const int aggblocks = (GN + 3) / 4;

    // ---- CSR build ----
    hipMemsetAsync(wpos, 0, GN * sizeof(int), stream);
    k_hist<<<eb, 256, 0, stream>>>(dst, wpos, GE);
    k_scan1<<<nb, 256, 0, stream>>>(wpos, row_ptr, partials, GN);
    k_scan2<<<1, 256, 0, stream>>>(partials, nb);
    k_scan3<<<nb, 256, 0, stream>>>(row_ptr, wpos, partials, GN, GE);
    k_fill<<<eb, 256, 0, stream>>>(src, dst, wpos, csr_src, GE);

    // ---- weights convert ----
    k_cvt_w<<<128, 256, 0, stream>>>(W0, W1, wbt);

    // ---- layer 1 (GEMM fuses el/er; agg fuses softmax-weight + ELU) ----
    gemm_mfma32<<<gblocks, 256, 0, stream>>>(inputs, target, wbt, al0, ar0,
                                             featb, el, er, NP);
    gat_agg_l1<<<aggblocks, 256, 0, stream>>>(featb, el, er, row_ptr, csr_src, abuf);

    // ---- layer 2 (agg fuses residual + ELU + mixup + h-write + logits) ----
    gemm_mfma<<<gblocks, 256, 0, stream>>>(abuf, wbt + 128 * 128, al1, ar1,
                                           featb, el, er, NP);
    gat_agg_l2<<<aggblocks, 256, 0, stream>>>(featb, el, er, row_ptr, csr_src,
                                              abuf, Wout, bout, lamb, outh, outlog);
}

// Round 9
// 443.598 us; speedup vs baseline: 1.2439x; 1.2439x over previous
//
#include <hip/hip_runtime.h>
#include <hip/hip_bf16.h>
#include <cstddef>

#define GN 50000
#define GE 800000
#define GH 4
#define GD 32
#define SLOPE 0.2f

typedef unsigned short ushort_t;
typedef unsigned int uint_t;
using short8 = __attribute__((ext_vector_type(8))) short;
using float4v = __attribute__((ext_vector_type(4))) float;

__device__ __forceinline__ ushort_t f2bf(float f) {
    union { float f; uint_t u; } v; v.f = f;
    uint_t r = v.u + 0x7fff + ((v.u >> 16) & 1);   // RNE
    return (ushort_t)(r >> 16);
}
__device__ __forceinline__ float bflo(uint_t u) { return __uint_as_float(u << 16); }
__device__ __forceinline__ float bfhi(uint_t u) { return __uint_as_float(u & 0xffff0000u); }
__device__ __forceinline__ float bfu(ushort_t u) { return __uint_as_float((uint_t)u << 16); }

// ---------------- CSR build ----------------
__global__ void k_hist(const int* __restrict__ dst, int* __restrict__ deg, int E) {
    int i = blockIdx.x * 256 + threadIdx.x;
    if (i < E) atomicAdd(&deg[dst[i]], 1);
}

__global__ void k_scan1(const int* __restrict__ deg, int* __restrict__ row_ptr,
                        int* __restrict__ partials, int n) {
    __shared__ int s[256];
    int t = threadIdx.x;
    int i = blockIdx.x * 256 + t;
    int v = (i < n) ? deg[i] : 0;
    s[t] = v;
    __syncthreads();
    for (int off = 1; off < 256; off <<= 1) {
        int add = (t >= off) ? s[t - off] : 0;
        __syncthreads();
        s[t] += add;
        __syncthreads();
    }
    if (i < n) row_ptr[i] = s[t] - v;
    if (t == 255) partials[blockIdx.x] = s[255];
}

__global__ void k_scan2(int* __restrict__ partials, int nb) {
    __shared__ int s[256];
    int t = threadIdx.x;
    int v = (t < nb) ? partials[t] : 0;
    s[t] = v;
    __syncthreads();
    for (int off = 1; off < 256; off <<= 1) {
        int add = (t >= off) ? s[t - off] : 0;
        __syncthreads();
        s[t] += add;
        __syncthreads();
    }
    if (t < nb) partials[t] = s[t] - v;
}

__global__ void k_scan3(int* __restrict__ row_ptr, int* __restrict__ wpos,
                        const int* __restrict__ partials, int n, int E) {
    int i = blockIdx.x * 256 + threadIdx.x;
    if (i < n) {
        int rp = row_ptr[i] + partials[i >> 8];
        row_ptr[i] = rp;
        wpos[i] = rp;
        if (i == 0) row_ptr[n] = E;
    }
}

__global__ void k_fill(const int* __restrict__ src, const int* __restrict__ dst,
                       int* __restrict__ wpos, int* __restrict__ csr_src, int E) {
    int i = blockIdx.x * 256 + threadIdx.x;
    if (i < E) {
        int p = atomicAdd(&wpos[dst[i]], 1);
        csr_src[p] = src[i];
    }
}

// ---------------- weight transpose+convert ----------------
__global__ void k_cvt_w(const float* __restrict__ W0, const float* __restrict__ W1,
                        ushort_t* __restrict__ wbt) {
    int t = blockIdx.x * 256 + threadIdx.x;   // 0..32767
    int m = t >> 14;
    int o = t & 16383;
    int n = o >> 7, k = o & 127;
    const float* W = m ? W1 : W0;
    wbt[t] = f2bf(W[k * 128 + n]);
}

// ---- fused el/er epilogue over MFMA accumulator ----
__device__ __forceinline__ void lr_epilogue(const float4v acc[2][8],
                                            const float* __restrict__ al,
                                            const float* __restrict__ ar,
                                            float* __restrict__ el,
                                            float* __restrict__ er,
                                            int r0, int quad, int col, int M) {
#pragma unroll
    for (int rt = 0; rt < 2; rt++) {
#pragma unroll
        for (int h = 0; h < 4; h++) {
            float alv0 = al[h * 32 + col], alv1 = al[h * 32 + 16 + col];
            float arv0 = ar[h * 32 + col], arv1 = ar[h * 32 + 16 + col];
            float pl[4], pr[4];
#pragma unroll
            for (int r = 0; r < 4; r++) {
                pl[r] = acc[rt][2 * h][r] * alv0 + acc[rt][2 * h + 1][r] * alv1;
                pr[r] = acc[rt][2 * h][r] * arv0 + acc[rt][2 * h + 1][r] * arv1;
            }
#pragma unroll
            for (int m = 1; m < 16; m <<= 1) {
#pragma unroll
                for (int r = 0; r < 4; r++) {
                    pl[r] += __shfl_xor(pl[r], m, 64);
                    pr[r] += __shfl_xor(pr[r], m, 64);
                }
            }
            if (col == h) {
#pragma unroll
                for (int r = 0; r < 4; r++) {
                    int row = r0 + rt * 16 + quad * 4 + r;
                    if (row < M) el[row * 4 + h] = pl[r];
                }
            }
            if (col == 8 + h) {
#pragma unroll
                for (int r = 0; r < 4; r++) {
                    int row = r0 + rt * 16 + quad * 4 + r;
                    if (row < M) er[row * 4 + h] = pr[r];
                }
            }
        }
    }
}

// ---------------- MFMA GEMM (fp32 A, layer 1) + fused el/er ----------------
__global__ __launch_bounds__(256) void gemm_mfma32(const float* __restrict__ A0,
                                                   const float* __restrict__ A1,
                                                   const ushort_t* __restrict__ WbT,
                                                   const float* __restrict__ al,
                                                   const float* __restrict__ ar,
                                                   ushort_t* __restrict__ Cb,
                                                   float* __restrict__ el,
                                                   float* __restrict__ er, int M) {
    __shared__ ushort_t Bs[128][136];
    int tid = threadIdx.x;
    for (int i = tid; i < 128 * 16; i += 256) {
        int n = i >> 4;
        int kc = (i & 15) << 3;
        *(short8*)&Bs[n][kc] = *(const short8*)&WbT[n * 128 + kc];
    }
    __syncthreads();
    int wid = tid >> 6, lane = tid & 63;
    int r0 = blockIdx.x * 128 + wid * 32;
    int col = lane & 15, quad = lane >> 4;
    float4v acc[2][8];
#pragma unroll
    for (int rt = 0; rt < 2; rt++)
#pragma unroll
        for (int t = 0; t < 8; t++) acc[rt][t] = (float4v){0.f, 0.f, 0.f, 0.f};
    int ar_[2] = {r0 + col, r0 + 16 + col};
    const float* Ap[2];
#pragma unroll
    for (int rt = 0; rt < 2; rt++) {
        int a = ar_[rt];
        Ap[rt] = (a < M) ? ((a < GN) ? (A0 + (size_t)a * 128)
                                     : (A1 + (size_t)(a - GN) * 128)) : nullptr;
    }
#pragma unroll
    for (int ks = 0; ks < 4; ks++) {
        short8 af[2];
#pragma unroll
        for (int rt = 0; rt < 2; rt++) {
            af[rt] = (short8){};
            if (Ap[rt]) {
                float4 v0 = *(const float4*)&Ap[rt][ks * 32 + quad * 8];
                float4 v1 = *(const float4*)&Ap[rt][ks * 32 + quad * 8 + 4];
                af[rt][0] = (short)f2bf(v0.x); af[rt][1] = (short)f2bf(v0.y);
                af[rt][2] = (short)f2bf(v0.z); af[rt][3] = (short)f2bf(v0.w);
                af[rt][4] = (short)f2bf(v1.x); af[rt][5] = (short)f2bf(v1.y);
                af[rt][6] = (short)f2bf(v1.z); af[rt][7] = (short)f2bf(v1.w);
            }
        }
#pragma unroll
        for (int nt = 0; nt < 8; nt++) {
            short8 bf = *(const short8*)&Bs[nt * 16 + col][ks * 32 + quad * 8];
            acc[0][nt] = __builtin_amdgcn_mfma_f32_16x16x32_bf16(af[0], bf, acc[0][nt], 0, 0, 0);
            acc[1][nt] = __builtin_amdgcn_mfma_f32_16x16x32_bf16(af[1], bf, acc[1][nt], 0, 0, 0);
        }
    }
#pragma unroll
    for (int rt = 0; rt < 2; rt++)
#pragma unroll
        for (int nt = 0; nt < 8; nt++)
#pragma unroll
            for (int r = 0; r < 4; r++) {
                int row = r0 + rt * 16 + quad * 4 + r;
                if (row < M) Cb[(size_t)row * 128 + nt * 16 + col] = f2bf(acc[rt][nt][r]);
            }
    lr_epilogue(acc, al, ar, el, er, r0, quad, col, M);
}

// ---------------- MFMA GEMM (bf16 A, layer 2) + fused el/er ----------------
__global__ __launch_bounds__(256) void gemm_mfma(const ushort_t* __restrict__ A,
                                                 const ushort_t* __restrict__ WbT,
                                                 const float* __restrict__ al,
                                                 const float* __restrict__ ar,
                                                 ushort_t* __restrict__ Cb,
                                                 float* __restrict__ el,
                                                 float* __restrict__ er, int M) {
    __shared__ ushort_t Bs[128][136];
    int tid = threadIdx.x;
    for (int i = tid; i < 128 * 16; i += 256) {
        int n = i >> 4;
        int kc = (i & 15) << 3;
        *(short8*)&Bs[n][kc] = *(const short8*)&WbT[n * 128 + kc];
    }
    __syncthreads();
    int wid = tid >> 6, lane = tid & 63;
    int r0 = blockIdx.x * 128 + wid * 32;
    int col = lane & 15, quad = lane >> 4;
    float4v acc[2][8];
#pragma unroll
    for (int rt = 0; rt < 2; rt++)
#pragma unroll
        for (int t = 0; t < 8; t++) acc[rt][t] = (float4v){0.f, 0.f, 0.f, 0.f};
    int ar_[2] = {r0 + col, r0 + 16 + col};
#pragma unroll
    for (int ks = 0; ks < 4; ks++) {
        short8 af[2];
#pragma unroll
        for (int rt = 0; rt < 2; rt++) {
            af[rt] = (short8){};
            if (ar_[rt] < M) af[rt] = *(const short8*)&A[(size_t)ar_[rt] * 128 + ks * 32 + quad * 8];
        }
#pragma unroll
        for (int nt = 0; nt < 8; nt++) {
            short8 bf = *(const short8*)&Bs[nt * 16 + col][ks * 32 + quad * 8];
            acc[0][nt] = __builtin_amdgcn_mfma_f32_16x16x32_bf16(af[0], bf, acc[0][nt], 0, 0, 0);
            acc[1][nt] = __builtin_amdgcn_mfma_f32_16x16x32_bf16(af[1], bf, acc[1][nt], 0, 0, 0);
        }
    }
#pragma unroll
    for (int rt = 0; rt < 2; rt++)
#pragma unroll
        for (int nt = 0; nt < 8; nt++)
#pragma unroll
            for (int r = 0; r < 4; r++) {
                int row = r0 + rt * 16 + quad * 4 + r;
                if (row < M) Cb[(size_t)row * 128 + nt * 16 + col] = f2bf(acc[rt][nt][r]);
            }
    lr_epilogue(acc, al, ar, el, er, r0, quad, col, M);
}

// ---- shared agg gather core: one wave per node, lanes 0-31 path0, 32-63 path1.
// lane q owns dims 4q..4q+3; head=q>>3. Softmax weight computed in-place
// (exp(leaky(el+er)), no max-sub: |e| small). Returns post-softmax v0..v3.
__device__ __forceinline__ void agg_core(
    const ushort_t* __restrict__ featb, const float* __restrict__ el, float ern,
    const int* __restrict__ csr_src, int base, int deg, int head, int q4,
    float& v0, float& v1, float& v2, float& v3) {
    float a0 = 0.f, a1 = 0.f, a2 = 0.f, a3 = 0.f, ss = 0.f;
    int i = 0;
    for (; i + 8 <= deg; i += 8) {
        int j = base + i;
        int s0 = csr_src[j + 0], s1 = csr_src[j + 1], s2 = csr_src[j + 2], s3 = csr_src[j + 3];
        int s4 = csr_src[j + 4], s5 = csr_src[j + 5], s6 = csr_src[j + 6], s7 = csr_src[j + 7];
        float e0 = el[s0 * 4 + head] + ern;
        float e1 = el[s1 * 4 + head] + ern;
        float e2 = el[s2 * 4 + head] + ern;
        float e3 = el[s3 * 4 + head] + ern;
        float e4 = el[s4 * 4 + head] + ern;
        float e5 = el[s5 * 4 + head] + ern;
        float e6 = el[s6 * 4 + head] + ern;
        float e7 = el[s7 * 4 + head] + ern;
        uint2 f0 = *(const uint2*)&featb[s0 * 128 + q4];
        uint2 f1 = *(const uint2*)&featb[s1 * 128 + q4];
        uint2 f2 = *(const uint2*)&featb[s2 * 128 + q4];
        uint2 f3 = *(const uint2*)&featb[s3 * 128 + q4];
        uint2 f4 = *(const uint2*)&featb[s4 * 128 + q4];
        uint2 f5 = *(const uint2*)&featb[s5 * 128 + q4];
        uint2 f6 = *(const uint2*)&featb[s6 * 128 + q4];
        uint2 f7 = *(const uint2*)&featb[s7 * 128 + q4];
        e0 = e0 > 0.f ? e0 : SLOPE * e0;
        e1 = e1 > 0.f ? e1 : SLOPE * e1;
        e2 = e2 > 0.f ? e2 : SLOPE * e2;
        e3 = e3 > 0.f ? e3 : SLOPE * e3;
        e4 = e4 > 0.f ? e4 : SLOPE * e4;
        e5 = e5 > 0.f ? e5 : SLOPE * e5;
        e6 = e6 > 0.f ? e6 : SLOPE * e6;
        e7 = e7 > 0.f ? e7 : SLOPE * e7;
        float w0 = __expf(e0), w1 = __expf(e1), w2 = __expf(e2), w3 = __expf(e3);
        float w4 = __expf(e4), w5 = __expf(e5), w6 = __expf(e6), w7 = __expf(e7);
        ss += ((w0 + w1) + (w2 + w3)) + ((w4 + w5) + (w6 + w7));
        a0 += w0 * bflo(f0.x) + w1 * bflo(f1.x) + w2 * bflo(f2.x) + w3 * bflo(f3.x) +
              w4 * bflo(f4.x) + w5 * bflo(f5.x) + w6 * bflo(f6.x) + w7 * bflo(f7.x);
        a1 += w0 * bfhi(f0.x) + w1 * bfhi(f1.x) + w2 * bfhi(f2.x) + w3 * bfhi(f3.x) +
              w4 * bfhi(f4.x) + w5 * bfhi(f5.x) + w6 * bfhi(f6.x) + w7 * bfhi(f7.x);
        a2 += w0 * bflo(f0.y) + w1 * bflo(f1.y) + w2 * bflo(f2.y) + w3 * bflo(f3.y) +
              w4 * bflo(f4.y) + w5 * bflo(f5.y) + w6 * bflo(f6.y) + w7 * bflo(f7.y);
        a3 += w0 * bfhi(f0.y) + w1 * bfhi(f1.y) + w2 * bfhi(f2.y) + w3 * bfhi(f3.y) +
              w4 * bfhi(f4.y) + w5 * bfhi(f5.y) + w6 * bfhi(f6.y) + w7 * bfhi(f7.y);
    }
    for (; i < deg; i++) {
        int j = base + i;
        int s = csr_src[j];
        float e = el[s * 4 + head] + ern;
        uint2 f = *(const uint2*)&featb[s * 128 + q4];
        e = e > 0.f ? e : SLOPE * e;
        float w = __expf(e);
        ss += w;
        a0 += w * bflo(f.x);
        a1 += w * bfhi(f.x);
        a2 += w * bflo(f.y);
        a3 += w * bfhi(f.y);
    }
    float inv = (deg > 0) ? 1.f / ss : 0.f;
    v0 = a0 * inv; v1 = a1 * inv; v2 = a2 * inv; v3 = a3 * inv;
}

// ---------------- layer-1 aggregate: -> abuf (bf16) ----------------
__global__ __launch_bounds__(256) void gat_agg_l1(
    const ushort_t* __restrict__ featb, const float* __restrict__ el,
    const float* __restrict__ er, const int* __restrict__ row_ptr,
    const int* __restrict__ csr_src, ushort_t* __restrict__ abuf) {
    int n = blockIdx.x * 4 + (threadIdx.x >> 6);
    if (n >= GN) return;
    int lane = threadIdx.x & 63;
    int half = lane >> 5;
    int q = lane & 31;
    int head = q >> 3, q4 = q << 2;
    const ushort_t* fb = featb + (size_t)half * (GN * 128);
    const float* elp = el + (size_t)half * (GN * 4);
    float ern = er[((size_t)n + (size_t)half * GN) * 4 + head];
    int base = row_ptr[n];
    int deg = row_ptr[n + 1] - base;
    float v0, v1, v2, v3;
    agg_core(fb, elp, ern, csr_src, base, deg, head, q4, v0, v1, v2, v3);
    v0 = v0 > 0.f ? v0 : __expf(v0) - 1.f;
    v1 = v1 > 0.f ? v1 : __expf(v1) - 1.f;
    v2 = v2 > 0.f ? v2 : __expf(v2) - 1.f;
    v3 = v3 > 0.f ? v3 : __expf(v3) - 1.f;
    size_t idx = ((size_t)n + (size_t)half * GN) * 128 + q4;
    ushort4 o;
    o.x = f2bf(v0); o.y = f2bf(v1); o.z = f2bf(v2); o.w = f2bf(v3);
    *(ushort4*)&abuf[idx] = o;
}

// ---------------- layer-2 aggregate + residual + ELU + mixup + h + logits ----------------
// Ws stays in Wout's native [k][40] layout: lanes read Ws[k*40+lane] ->
// consecutive banks, only lane0/lane32 alias (2-way = free). hs reads broadcast.
__global__ __launch_bounds__(256) void gat_agg_l2(
    const ushort_t* __restrict__ featb, const float* __restrict__ el,
    const float* __restrict__ er, const int* __restrict__ row_ptr,
    const int* __restrict__ csr_src, const ushort_t* __restrict__ resid,
    const float* __restrict__ Wout, const float* __restrict__ bout,
    const float* __restrict__ lamb, float* __restrict__ outh,
    float* __restrict__ outlog) {
    __shared__ float Ws[128 * 40];    // native layout: Ws[k*40+c]
    __shared__ float bs[40];
    __shared__ float hs[4][128];
    int tid = threadIdx.x;
    for (int i = tid; i < 128 * 40; i += 256) Ws[i] = Wout[i];
    if (tid < 40) bs[tid] = bout[tid];
    __syncthreads();
    int n = blockIdx.x * 4 + (tid >> 6);
    if (n >= GN) return;
    int w = tid >> 6;
    int lane = tid & 63;
    int half = lane >> 5;
    int q = lane & 31;
    int head = q >> 3, q4 = q << 2;
    const ushort_t* fb = featb + (size_t)half * (GN * 128);
    const float* elp = el + (size_t)half * (GN * 4);
    float ern = er[((size_t)n + (size_t)half * GN) * 4 + head];
    int base = row_ptr[n];
    int deg = row_ptr[n + 1] - base;
    float v0, v1, v2, v3;
    agg_core(fb, elp, ern, csr_src, base, deg, head, q4, v0, v1, v2, v3);
    // residual (bf16) + ELU
    size_t idx = ((size_t)n + (size_t)half * GN) * 128 + q4;
    ushort4 r = *(const ushort4*)&resid[idx];
    v0 += bfu(r.x); v1 += bfu(r.y); v2 += bfu(r.z); v3 += bfu(r.w);
    v0 = v0 > 0.f ? v0 : __expf(v0) - 1.f;
    v1 = v1 > 0.f ? v1 : __expf(v1) - 1.f;
    v2 = v2 > 0.f ? v2 : __expf(v2) - 1.f;
    v3 = v3 > 0.f ? v3 : __expf(v3) - 1.f;
    // mixup across halves (partner lane = lane ^ 32)
    float p0 = __shfl_xor(v0, 32, 64);
    float p1 = __shfl_xor(v1, 32, 64);
    float p2 = __shfl_xor(v2, 32, 64);
    float p3 = __shfl_xor(v3, 32, 64);
    float lam = lamb[0];
    if (half == 0) {
        float m0 = lam * v0 + (1.f - lam) * p0;
        float m1 = lam * v1 + (1.f - lam) * p1;
        float m2 = lam * v2 + (1.f - lam) * p2;
        float m3 = lam * v3 + (1.f - lam) * p3;
        *(float4*)&outh[(size_t)n * 128 + q4] = make_float4(m0, m1, m2, m3);
        *(float4*)&hs[w][q4] = make_float4(m0, m1, m2, m3);
    }
    // logits: lanes 0..39 each compute one class (same-wave LDS, no barrier)
    if (lane < 40) {
        float acc = bs[lane];
#pragma unroll 8
        for (int k = 0; k < 128; k++) acc += hs[w][k] * Ws[k * 40 + lane];
        outlog[(size_t)n * 40 + lane] = acc;
    }
}

extern "C" void kernel_launch(void* const* d_in, const int* in_sizes, int n_in,
                              void* d_out, int out_size, void* d_ws, size_t ws_size,
                              hipStream_t stream) {
    const float* inputs = (const float*)d_in[0];
    const float* target = (const float*)d_in[1];
    const float* lamb   = (const float*)d_in[2];
    const float* W0     = (const float*)d_in[3];
    const float* al0    = (const float*)d_in[4];
    const float* ar0    = (const float*)d_in[5];
    const float* W1     = (const float*)d_in[6];
    const float* al1    = (const float*)d_in[7];
    const float* ar1    = (const float*)d_in[8];
    const float* Wout   = (const float*)d_in[9];
    const float* bout   = (const float*)d_in[10];
    const int*   src    = (const int*)d_in[11];
    const int*   dst    = (const int*)d_in[12];

    float* out = (float*)d_out;
    float* outh = out;                          // [N,128]
    float* outlog = out + (size_t)GN * 128;     // [N,40]

    const int NP = 2 * GN;
    // workspace layout
    ushort_t* featb = (ushort_t*)d_ws;                    // [2N,128] bf16
    ushort_t* abuf  = featb + (size_t)NP * 128;           // [2N,128] bf16 (layer1 out / resid)
    float* el = (float*)(abuf + (size_t)NP * 128);        // [2N,4]
    float* er = el + (size_t)NP * GH;                     // [2N,4]
    ushort_t* wbt = (ushort_t*)(er + (size_t)NP * GH);    // [2][128][128] bf16
    int* row_ptr  = (int*)(wbt + 2 * 128 * 128);          // N+1
    int* wpos     = row_ptr + (GN + 1);                   // N
    int* csr_src  = wpos + GN;                            // E (+pad)
    int* partials = csr_src + GE + 16;                    // 256

    const int nb = (GN + 255) / 256;
    const int eb = (GE + 255) / 256;
    const int gblocks = (NP + 127) / 128;
    const int aggblocks = (GN + 3) / 4;

    // ---- CSR build ----
    hipMemsetAsync(wpos, 0, GN * sizeof(int), stream);
    k_hist<<<eb, 256, 0, stream>>>(dst, wpos, GE);
    k_scan1<<<nb, 256, 0, stream>>>(wpos, row_ptr, partials, GN);
    k_scan2<<<1, 256, 0, stream>>>(partials, nb);
    k_scan3<<<nb, 256, 0, stream>>>(row_ptr, wpos, partials, GN, GE);
    k_fill<<<eb, 256, 0, stream>>>(src, dst, wpos, csr_src, GE);

    // ---- weights convert ----
    k_cvt_w<<<128, 256, 0, stream>>>(W0, W1, wbt);

    // ---- layer 1 (GEMM fuses el/er; agg fuses softmax-weight + ELU) ----
    gemm_mfma32<<<gblocks, 256, 0, stream>>>(inputs, target, wbt, al0, ar0,
                                             featb, el, er, NP);
    gat_agg_l1<<<aggblocks, 256, 0, stream>>>(featb, el, er, row_ptr, csr_src, abuf);

    // ---- layer 2 (agg fuses residual + ELU + mixup + h-write + logits) ----
    gemm_mfma<<<gblocks, 256, 0, stream>>>(abuf, wbt + 128 * 128, al1, ar1,
                                           featb, el, er, NP);
    gat_agg_l2<<<aggblocks, 256, 0, stream>>>(featb, el, er, row_ptr, csr_src,
                                              abuf, Wout, bout, lamb, outh, outlog);
}